// Round 1
// baseline (1069.494 us; speedup 1.0000x reference)
//
#include <hip/hip_runtime.h>
#include <math.h>

#define NUM_NODES 150000
#define DIM 64
#define N_EDGES 3200000
#define BATCH 1024
#define N_NEGS 40
#define REG_COEF 1e-4f
#define SCAN_B 1024
#define NB ((NUM_NODES + SCAN_B - 1) / SCAN_B)   // 147

// ---------------- degree count ----------------
__global__ void count_deg_kernel(const int* __restrict__ col, int* __restrict__ deg) {
    int e = blockIdx.x * blockDim.x + threadIdx.x;
    if (e < N_EDGES) atomicAdd(&deg[col[e]], 1);
}

// ---------------- scan (3 kernels) ----------------
__global__ void scan_partial_kernel(const int* __restrict__ deg, int* __restrict__ partial) {
    int t = threadIdx.x;
    int g = blockIdx.x * SCAN_B + t;
    int v = (g < NUM_NODES) ? deg[g] : 0;
    for (int m = 1; m < 64; m <<= 1) v += __shfl_xor(v, m);
    __shared__ int ws[16];
    if ((t & 63) == 0) ws[t >> 6] = v;
    __syncthreads();
    if (t < 16) {
        int s = ws[t];
        for (int m = 1; m < 16; m <<= 1) s += __shfl_xor(s, m);
        if (t == 0) partial[blockIdx.x] = s;
    }
}

__global__ void scan_base_kernel(int* __restrict__ partial) {
    // single wave, 3 chunks of 64 covering NB=147
    int l = threadIdx.x;
    int carry = 0;
    for (int c = 0; c < 3; c++) {
        int idx = c * 64 + l;
        int v = (idx < NB) ? partial[idx] : 0;
        int inc = v;
        for (int m = 1; m < 64; m <<= 1) {
            int t = __shfl_up(inc, m);
            if (l >= m) inc += t;
        }
        int excl = inc - v + carry;
        if (idx < NB) partial[idx] = excl;
        carry += __shfl(inc, 63);
    }
}

__global__ void scan_apply_kernel(const int* __restrict__ deg, const int* __restrict__ partial,
                                  int* __restrict__ off) {
    __shared__ int lds[SCAN_B];
    int t = threadIdx.x;
    int g = blockIdx.x * SCAN_B + t;
    int v = (g < NUM_NODES) ? deg[g] : 0;
    int val = v;
    lds[t] = val;
    __syncthreads();
    for (int o = 1; o < SCAN_B; o <<= 1) {
        int add = (t >= o) ? lds[t - o] : 0;
        __syncthreads();
        val += add;
        lds[t] = val;
        __syncthreads();
    }
    if (g < NUM_NODES) off[g] = partial[blockIdx.x] + val - v;  // exclusive (start)
}

// ---------------- dinv ----------------
__global__ void dinv_kernel(const int* __restrict__ deg, float* __restrict__ dinv) {
    int g = blockIdx.x * blockDim.x + threadIdx.x;
    if (g < NUM_NODES) {
        int d = deg[g];
        dinv[g] = (d > 0) ? rsqrtf((float)d) : 0.f;
    }
}

// ---------------- CSR fill (advances off[c] from start -> end) ----------------
__global__ void fill_kernel(const int* __restrict__ row, const int* __restrict__ col,
                            int* __restrict__ off, int* __restrict__ csr_row) {
    int e = blockIdx.x * blockDim.x + threadIdx.x;
    if (e < N_EDGES) {
        int c = col[e];
        int pos = atomicAdd(&off[c], 1);
        csr_row[pos] = row[e];
    }
}

// ---------------- conv: y[c] = dinv[c] * sum_{e in-edges of c} dinv[row] * x[row]
// one wave per node, lane = dim. After fill, off[c] == end(c); start(c) = off[c-1].
__global__ __launch_bounds__(256) void conv_kernel(const int* __restrict__ off,
                                                   const int* __restrict__ csr_row,
                                                   const float* __restrict__ dinv,
                                                   const float* __restrict__ x,
                                                   float* __restrict__ y) {
    int wid = (blockIdx.x * blockDim.x + threadIdx.x) >> 6;
    int lane = threadIdx.x & 63;
    if (wid >= NUM_NODES) return;
    int start = (wid == 0) ? 0 : off[wid - 1];
    int end = off[wid];
    float acc = 0.f;
    int i = start;
    for (; i + 1 < end; i += 2) {
        int r0 = csr_row[i];
        int r1 = csr_row[i + 1];
        float d0 = dinv[r0];
        float d1 = dinv[r1];
        float v0 = x[(size_t)r0 * DIM + lane];
        float v1 = x[(size_t)r1 * DIM + lane];
        acc += d0 * v0 + d1 * v1;
    }
    if (i < end) {
        int r0 = csr_row[i];
        acc += dinv[r0] * x[(size_t)r0 * DIM + lane];
    }
    y[(size_t)wid * DIM + lane] = acc * dinv[wid];
}

// ---------------- fused node-wise: z_p avg, MLP, attention, Z ----------------
__global__ __launch_bounds__(256) void fuse_kernel(
    const float* __restrict__ E, const float* __restrict__ E2,
    const float* __restrict__ W0, const float* __restrict__ b0,
    const float* __restrict__ W1, const float* __restrict__ b1,
    const float* __restrict__ AW, const float* __restrict__ ab,
    const float* __restrict__ qW,
    const float* x1, const float* x2, float* Z) {
    __shared__ __align__(16) float W0q[4096];
    __shared__ __align__(16) float W1q[4096];
    __shared__ __align__(16) float AWq[4096];
    __shared__ float bb0[64], bb1[64], bab[64], qb[64];
    __shared__ __align__(16) float xbuf[4][64];
    __shared__ __align__(16) float hbuf[4][64];
    __shared__ __align__(16) float zpb[4][64];
    __shared__ __align__(16) float znb[4][64];

    int t = threadIdx.x;
    // stage transposed-with-quad-interleave weights: Wq[(k/4)*256 + j*4 + k%4] = W[j*64+k]
    for (int idx = t; idx < 4096; idx += 256) {
        int j = idx >> 6, k = idx & 63;
        int dst = (k >> 2) * 256 + j * 4 + (k & 3);
        W0q[dst] = W0[idx];
        W1q[dst] = W1[idx];
        AWq[dst] = AW[idx];
    }
    if (t < 64) { bb0[t] = b0[t]; bb1[t] = b1[t]; bab[t] = ab[t]; qb[t] = qW[t]; }
    __syncthreads();

    const int lane = t & 63, w = t >> 6;
    for (int nd = blockIdx.x * 4 + w; nd < NUM_NODES; nd += gridDim.x * 4) {
        size_t base = (size_t)nd * DIM + lane;
        float zp = (E[base] + x1[base] + x2[base]) * (1.f / 3.f);
        float e2v = E2[base];
        zpb[w][lane] = zp;
        xbuf[w][lane] = e2v;
        __syncthreads();

        // h = relu(E2 @ W0.T + b0)
        float s = bb0[lane];
#pragma unroll
        for (int k4 = 0; k4 < 16; k4++) {
            float4 wq = *(const float4*)&W0q[k4 * 256 + lane * 4];
            float4 xq = *(const float4*)&xbuf[w][k4 * 4];
            s += wq.x * xq.x + wq.y * xq.y + wq.z * xq.z + wq.w * xq.w;
        }
        float h = fmaxf(s, 0.f);
        hbuf[w][lane] = h;
        __syncthreads();

        // z_n = relu(h @ W1.T + b1)
        s = bb1[lane];
#pragma unroll
        for (int k4 = 0; k4 < 16; k4++) {
            float4 wq = *(const float4*)&W1q[k4 * 256 + lane * 4];
            float4 xq = *(const float4*)&hbuf[w][k4 * 4];
            s += wq.x * xq.x + wq.y * xq.y + wq.z * xq.z + wq.w * xq.w;
        }
        float zn = fmaxf(s, 0.f);
        znb[w][lane] = zn;
        __syncthreads();

        // attention scores
        float sp = bab[lane], sn = bab[lane];
#pragma unroll
        for (int k4 = 0; k4 < 16; k4++) {
            float4 wq = *(const float4*)&AWq[k4 * 256 + lane * 4];
            float4 zq = *(const float4*)&zpb[w][k4 * 4];
            float4 nq = *(const float4*)&znb[w][k4 * 4];
            sp += wq.x * zq.x + wq.y * zq.y + wq.z * zq.z + wq.w * zq.w;
            sn += wq.x * nq.x + wq.y * nq.y + wq.z * nq.z + wq.w * nq.w;
        }
        float tp = tanhf(sp) * qb[lane];
        float tn = tanhf(sn) * qb[lane];
        for (int m = 1; m < 64; m <<= 1) {
            tp += __shfl_xor(tp, m);
            tn += __shfl_xor(tn, m);
        }
        float mx = fmaxf(tp, tn);
        float ep = expf(tp - mx), en = expf(tn - mx);
        float inv = 1.f / (ep + en);
        Z[base] = (ep * zp + en * zn) * inv;
        __syncthreads();
    }
}

// ---------------- loss ----------------
__global__ __launch_bounds__(256) void loss_kernel(const float* __restrict__ Z,
                                                   const float* __restrict__ wv,
                                                   const int* __restrict__ u,
                                                   const int* __restrict__ v,
                                                   const int* __restrict__ n,
                                                   float* __restrict__ out) {
    int wid = (blockIdx.x * blockDim.x + threadIdx.x) >> 6;
    int lane = threadIdx.x & 63;
    if (wid >= BATCH) return;
    float uu = Z[(size_t)u[wid] * DIM + lane];
    float vv = Z[(size_t)v[wid] * DIM + lane];
    float pos = uu * vv;
    for (int m = 1; m < 64; m <<= 1) pos += __shfl_xor(pos, m);
    float reg = uu * uu + vv * vv;
    float wval = wv[wid];
    float sgn = (wval > 0.f ? 1.f : 0.f) - (wval < 0.f ? 1.f : 0.f);
    float coef = -0.5f * sgn + 1.5f;
    float cp = coef * pos;
    float sb = 0.f;
    for (int k = 0; k < N_NEGS; k++) {
        int nid = n[wid * N_NEGS + k];
        float nn = Z[(size_t)nid * DIM + lane];
        float d = uu * nn;
        for (int m = 1; m < 64; m <<= 1) d += __shfl_xor(d, m);
        reg += nn * nn;
        float x = cp - d;
        float ls = (x >= 0.f) ? -log1pf(expf(-x)) : (x - log1pf(expf(x)));
        sb += ls;
    }
    for (int m = 1; m < 64; m <<= 1) reg += __shfl_xor(reg, m);
    if (lane == 0) atomicAdd(out, -sb + REG_COEF * reg);
}

extern "C" void kernel_launch(void* const* d_in, const int* in_sizes, int n_in,
                              void* d_out, int out_size, void* d_ws, size_t ws_size,
                              hipStream_t stream) {
    const float* E  = (const float*)d_in[0];
    const float* E2 = (const float*)d_in[1];
    const float* W0 = (const float*)d_in[2];
    const float* b0 = (const float*)d_in[3];
    const float* W1 = (const float*)d_in[4];
    const float* b1 = (const float*)d_in[5];
    const float* AW = (const float*)d_in[6];
    const float* ab = (const float*)d_in[7];
    const float* qW = (const float*)d_in[8];
    const float* wv = (const float*)d_in[9];
    const int* ei   = (const int*)d_in[10];
    const int* uu   = (const int*)d_in[11];
    const int* vv   = (const int*)d_in[12];
    const int* nn   = (const int*)d_in[13];
    const int* row = ei;
    const int* col = ei + N_EDGES;

    char* ws = (char*)d_ws;
    size_t p = 0;
    auto align_up = [](size_t x) { return (x + 255) & ~(size_t)255; };
    int* off      = (int*)(ws + p); p = align_up(p + (size_t)NUM_NODES * 4);
    int* deg      = (int*)(ws + p); p = align_up(p + (size_t)NUM_NODES * 4);
    float* dinv   = (float*)(ws + p); p = align_up(p + (size_t)NUM_NODES * 4);
    int* partial  = (int*)(ws + p); p = align_up(p + (size_t)NB * 4);
    int* csr_row  = (int*)(ws + p); p = align_up(p + (size_t)N_EDGES * 4);
    float* x1     = (float*)(ws + p); p = align_up(p + (size_t)NUM_NODES * DIM * 4);
    float* x2     = (float*)(ws + p); p = align_up(p + (size_t)NUM_NODES * DIM * 4);
    float* Z = x1;  // alias: fuse reads x1[i] then writes Z[i] in the same thread

    hipMemsetAsync(deg, 0, (size_t)NUM_NODES * 4, stream);
    hipMemsetAsync(d_out, 0, sizeof(float), stream);

    count_deg_kernel<<<(N_EDGES + 255) / 256, 256, 0, stream>>>(col, deg);
    scan_partial_kernel<<<NB, SCAN_B, 0, stream>>>(deg, partial);
    scan_base_kernel<<<1, 64, 0, stream>>>(partial);
    scan_apply_kernel<<<NB, SCAN_B, 0, stream>>>(deg, partial, off);
    dinv_kernel<<<(NUM_NODES + 255) / 256, 256, 0, stream>>>(deg, dinv);
    fill_kernel<<<(N_EDGES + 255) / 256, 256, 0, stream>>>(row, col, off, csr_row);

    conv_kernel<<<NUM_NODES / 4, 256, 0, stream>>>(off, csr_row, dinv, E, x1);
    conv_kernel<<<NUM_NODES / 4, 256, 0, stream>>>(off, csr_row, dinv, x1, x2);

    fuse_kernel<<<2048, 256, 0, stream>>>(E, E2, W0, b0, W1, b1, AW, ab, qW, x1, x2, Z);

    loss_kernel<<<BATCH * 64 / 256, 256, 0, stream>>>(Z, wv, uu, vv, nn, (float*)d_out);
}